// Round 8
// baseline (371.132 us; speedup 1.0000x reference)
//
#include <hip/hip_runtime.h>
#include <cstddef>

typedef unsigned short u16;
using short8 = __attribute__((ext_vector_type(8))) short;
using f32x4  = __attribute__((ext_vector_type(4))) float;

__device__ __forceinline__ float bf2f(u16 u) {
  union { unsigned int i; float f; } v; v.i = ((unsigned int)u) << 16; return v.f;
}
__device__ __forceinline__ u16 f2bf(float f) {
  __bf16 h = (__bf16)f;
  return __builtin_bit_cast(unsigned short, h);
}

// async global(16B/lane) -> LDS. lds dest must be wave-uniform base; HW adds lane*16.
__device__ __forceinline__ void load_lds16(const u16* g, u16* l) {
  __builtin_amdgcn_global_load_lds((const __attribute__((address_space(1))) void*)g,
                                   (__attribute__((address_space(3))) void*)l, 16, 0, 0);
}

// ---------------------------------------------------------------------------
// prep_k: ALL weight transposes (fp32 [R][C] -> bf16 [C][R]) + qkv bias concat.
// Block (32,8). Ranges: [0,3072) WQ/WK/WV; [3072,4096) W_O; [4096,8192) W_in;
// [8192,12288) W_out; 12288 bias concat.
// ---------------------------------------------------------------------------
__global__ __launch_bounds__(256) void prep_k(const float* __restrict__ wq,
                                              const float* __restrict__ wk,
                                              const float* __restrict__ wv,
                                              const float* __restrict__ wo,
                                              const float* __restrict__ win,
                                              const float* __restrict__ wout,
                                              const float* __restrict__ bq,
                                              const float* __restrict__ bk,
                                              const float* __restrict__ bv,
                                              u16* __restrict__ wqkvT,
                                              u16* __restrict__ woT,
                                              u16* __restrict__ winT,
                                              u16* __restrict__ woutT,
                                              float* __restrict__ qkvBias) {
  __shared__ float tile[32][33];
  int id = blockIdx.x;
  int tx = threadIdx.x, ty = threadIdx.y;

  if (id == 12288) {               // bias concat
    int t = ty * 32 + tx;
#pragma unroll
    for (int i = 0; i < 12; ++i) {
      int idx = i * 256 + t;
      float v = (idx < 1024) ? bq[idx] : (idx < 2048) ? bk[idx - 1024] : bv[idx - 2048];
      qkvBias[idx] = v;
    }
    return;
  }

  const float* in; u16* out; int R, C, c0, r0;
  if (id < 3072) {                 // W_Q / W_K / W_V, per-head
    int s = id >> 10, r = id & 1023;
    int h = r >> 6, tt = r & 63;
    const float* W = (s == 0) ? wq : (s == 1) ? wk : wv;
    in = W + h * 65536;
    out = wqkvT + (size_t)s * 1024 * 1024 + h * 64 * 1024;
    R = 1024; C = 64;
    c0 = (tt & 1) * 32; r0 = (tt >> 1) * 32;
  } else if (id < 4096) {          // W_O
    int tt = id - 3072;
    in = wo; out = woT; R = 1024; C = 1024;
    c0 = (tt & 31) * 32; r0 = (tt >> 5) * 32;
  } else if (id < 8192) {          // W_in
    int tt = id - 4096;
    in = win; out = winT; R = 1024; C = 4096;
    c0 = (tt & 127) * 32; r0 = (tt >> 7) * 32;
  } else {                         // W_out
    int tt = id - 8192;
    in = wout; out = woutT; R = 4096; C = 1024;
    c0 = (tt & 31) * 32; r0 = (tt >> 5) * 32;
  }

#pragma unroll
  for (int i = 0; i < 32; i += 8)
    tile[ty + i][tx] = in[(size_t)(r0 + ty + i) * C + c0 + tx];
  __syncthreads();
#pragma unroll
  for (int i = 0; i < 32; i += 8)
    out[(size_t)(c0 + ty + i) * R + r0 + tx] = f2bf(tile[tx][ty + i]);
}

// ---------------------------------------------------------------------------
// V transpose: qkv [b*2048][3072] (V at col 2048+h*64+e) -> vT[(b*16+h)*64+e][2048]
// Grid (2, 64, 32), block (32,8).
// ---------------------------------------------------------------------------
__global__ __launch_bounds__(256) void transpose_v_k(const u16* __restrict__ qkv,
                                                     u16* __restrict__ vT) {
  __shared__ u16 tile[32][33];
  int bh = blockIdx.z;
  int b = bh >> 4, h = bh & 15;
  const u16* in = qkv + (size_t)b * 2048 * 3072 + 2048 + h * 64;
  u16* out = vT + (size_t)bh * 64 * 2048;
  int e0 = blockIdx.x * 32, s0 = blockIdx.y * 32;
  int tx = threadIdx.x, ty = threadIdx.y;
#pragma unroll
  for (int i = 0; i < 32; i += 8)
    tile[ty + i][tx] = in[(size_t)(s0 + ty + i) * 3072 + e0 + tx];
  __syncthreads();
#pragma unroll
  for (int i = 0; i < 32; i += 8)
    out[(size_t)(e0 + ty + i) * 2048 + s0 + tx] = tile[tx][ty + i];
}

// ---------------------------------------------------------------------------
// LayerNorm over D=1024, fp32 in -> bf16 out. One block (256 thr) per row.
// ---------------------------------------------------------------------------
__global__ __launch_bounds__(256) void ln_k(const float* __restrict__ inp,
                                            const float* __restrict__ w,
                                            const float* __restrict__ bias,
                                            u16* __restrict__ out) {
  __shared__ float red[2][4];
  int row = blockIdx.x, t = threadIdx.x;
  int wave = t >> 6, lane = t & 63;
  size_t base = (size_t)row * 1024 + t * 4;
  float4 f = *(const float4*)(inp + base);
  float v[4] = {f.x, f.y, f.z, f.w};
  float s = v[0] + v[1] + v[2] + v[3];
#pragma unroll
  for (int off = 32; off; off >>= 1) s += __shfl_xor(s, off, 64);
  if (lane == 0) red[0][wave] = s;
  __syncthreads();
  float mean = (red[0][0] + red[0][1] + red[0][2] + red[0][3]) * (1.f / 1024.f);
  float c[4]; float sq = 0.f;
#pragma unroll
  for (int j = 0; j < 4; ++j) { c[j] = v[j] - mean; sq += c[j] * c[j]; }
#pragma unroll
  for (int off = 32; off; off >>= 1) sq += __shfl_xor(sq, off, 64);
  if (lane == 0) red[1][wave] = sq;
  __syncthreads();
  float var = (red[1][0] + red[1][1] + red[1][2] + red[1][3]) * (1.f / 1024.f);
  float inv = 1.f / sqrtf(var + 1e-5f);
  float4 wv = *(const float4*)(w + t * 4);
  float4 bv = *(const float4*)(bias + t * 4);
  out[base + 0] = f2bf(c[0] * inv * wv.x + bv.x);
  out[base + 1] = f2bf(c[1] * inv * wv.y + bv.y);
  out[base + 2] = f2bf(c[2] * inv * wv.z + bv.z);
  out[base + 3] = f2bf(c[3] * inv * wv.w + bv.w);
}

// ---------------------------------------------------------------------------
// Fused proj-split-merge + residual + LN2: one block per row.
// rm = resid_pre + b_O + p0 + p1 (bf16 partials); write resid_mid fp32 and
// LN(rm) -> xln bf16.
// ---------------------------------------------------------------------------
__global__ __launch_bounds__(256) void merge_ln_k(const u16* __restrict__ p,  // [2][4096][1024] bf16
                                                  const float* __restrict__ bO,
                                                  const float* __restrict__ resid_pre,
                                                  float* __restrict__ resid_mid,
                                                  const float* __restrict__ w,
                                                  const float* __restrict__ bias,
                                                  u16* __restrict__ out) {
  __shared__ float red[2][4];
  const size_t S = (size_t)4096 * 1024;
  int row = blockIdx.x, t = threadIdx.x;
  int wave = t >> 6, lane = t & 63;
  size_t base = (size_t)row * 1024 + t * 4;
  float4 f = *(const float4*)(resid_pre + base);
  float4 bo = *(const float4*)(bO + t * 4);
  ushort4 a0 = *(const ushort4*)(p + base);
  ushort4 a1 = *(const ushort4*)(p + S + base);
  float v[4];
  v[0] = f.x + bo.x + bf2f(a0.x) + bf2f(a1.x);
  v[1] = f.y + bo.y + bf2f(a0.y) + bf2f(a1.y);
  v[2] = f.z + bo.z + bf2f(a0.z) + bf2f(a1.z);
  v[3] = f.w + bo.w + bf2f(a0.w) + bf2f(a1.w);
  *(float4*)(resid_mid + base) = (float4){v[0], v[1], v[2], v[3]};
  float s = v[0] + v[1] + v[2] + v[3];
#pragma unroll
  for (int off = 32; off; off >>= 1) s += __shfl_xor(s, off, 64);
  if (lane == 0) red[0][wave] = s;
  __syncthreads();
  float mean = (red[0][0] + red[0][1] + red[0][2] + red[0][3]) * (1.f / 1024.f);
  float c[4]; float sq = 0.f;
#pragma unroll
  for (int j = 0; j < 4; ++j) { c[j] = v[j] - mean; sq += c[j] * c[j]; }
#pragma unroll
  for (int off = 32; off; off >>= 1) sq += __shfl_xor(sq, off, 64);
  if (lane == 0) red[1][wave] = sq;
  __syncthreads();
  float var = (red[1][0] + red[1][1] + red[1][2] + red[1][3]) * (1.f / 1024.f);
  float inv = 1.f / sqrtf(var + 1e-5f);
  float4 wv = *(const float4*)(w + t * 4);
  float4 bv = *(const float4*)(bias + t * 4);
  out[base + 0] = f2bf(c[0] * inv * wv.x + bv.x);
  out[base + 1] = f2bf(c[1] * inv * wv.y + bv.y);
  out[base + 2] = f2bf(c[2] * inv * wv.z + bv.z);
  out[base + 3] = f2bf(c[3] * inv * wv.w + bv.w);
}

// ---------------------------------------------------------------------------
// MLP-down split merge: out = resid_mid + b_out + p0 + p1. One block per row.
// ---------------------------------------------------------------------------
__global__ __launch_bounds__(256) void merge_out_k(const u16* __restrict__ p,  // [2][4096][1024] bf16
                                                   const float* __restrict__ bout,
                                                   const float* __restrict__ resid_mid,
                                                   float* __restrict__ out) {
  const size_t S = (size_t)4096 * 1024;
  int row = blockIdx.x, t = threadIdx.x;
  size_t base = (size_t)row * 1024 + t * 4;
  float4 f = *(const float4*)(resid_mid + base);
  float4 bo = *(const float4*)(bout + t * 4);
  ushort4 a0 = *(const ushort4*)(p + base);
  ushort4 a1 = *(const ushort4*)(p + S + base);
  float4 r;
  r.x = f.x + bo.x + bf2f(a0.x) + bf2f(a1.x);
  r.y = f.y + bo.y + bf2f(a0.y) + bf2f(a1.y);
  r.z = f.z + bo.z + bf2f(a0.z) + bf2f(a1.z);
  r.w = f.w + bo.w + bf2f(a0.w) + bf2f(a1.w);
  *(float4*)(out + base) = r;
}

// ---------------------------------------------------------------------------
// m97-class MFMA GEMM: C[M][N] = A[M][*](bf16) * BT[N][*](bf16)^T (+bias...).
// 128xTN tile, BK=64, global_load_lds staging, XOR-swizzled LDS.
// SPLIT: blockIdx.z selects K-slab [z*K, (z+1)*K); writes bf16 partial at
// Cout + z*M*N, no bias/gelu/resid. lda/ldb = row strides of A/BT.
// ---------------------------------------------------------------------------
template<int TN, bool RESIDF, bool GELU, bool OUTF32, bool SPLIT>
__global__ __launch_bounds__(256, 2) void gemm_k(const u16* __restrict__ A,
                                                 const u16* __restrict__ BT,
                                                 const float* __restrict__ bias,
                                                 const float* __restrict__ resid,
                                                 void* __restrict__ Cout,
                                                 int M, int N, int K,
                                                 int lda, int ldb) {
  constexpr int NS = TN / 32;
  __shared__ u16 As[128 * 64];
  __shared__ u16 Bs[TN * 64];
  int n0 = blockIdx.x * TN, m0 = blockIdx.y * 128;
  int koff = SPLIT ? blockIdx.z * K : 0;
  int t = threadIdx.x;
  int wave = t >> 6, lane = t & 63;
  int wr = wave >> 1, wc = wave & 1;
  int ln16 = lane & 15, quad = lane >> 4;

  f32x4 acc[4][NS];
#pragma unroll
  for (int i = 0; i < 4; ++i)
#pragma unroll
    for (int j = 0; j < NS; ++j) acc[i][j] = (f32x4){0.f, 0.f, 0.f, 0.f};

  int lrow8 = lane >> 3;
  int gseg  = (lane & 7) ^ lrow8;
  const u16* aG = A  + (size_t)(m0 + wave * 8 + lrow8) * lda + koff + gseg * 8;
  const u16* bG = BT + (size_t)(n0 + wave * 8 + lrow8) * ldb + koff + gseg * 8;
  u16* aL = As + wave * 8 * 64;
  u16* bL = Bs + wave * 8 * 64;

  int e = ln16 & 7;
  int arow = wr * 64 + ln16;
  int brow = wc * (TN / 2) + ln16;

  for (int k0 = 0; k0 < K; k0 += 64) {
    __syncthreads();
#pragma unroll
    for (int i = 0; i < 4; ++i)
      load_lds16(aG + (size_t)i * 32 * lda + k0, aL + i * 32 * 64);
#pragma unroll
    for (int i = 0; i < TN / 32; ++i)
      load_lds16(bG + (size_t)i * 32 * ldb + k0, bL + i * 32 * 64);
    __syncthreads();
#pragma unroll
    for (int kk = 0; kk < 2; ++kk) {
      int slot = (kk * 4 + quad) ^ e;
      short8 af[4], bf[NS];
#pragma unroll
      for (int ms = 0; ms < 4; ++ms)
        af[ms] = *(const short8*)&As[(arow + ms * 16) * 64 + slot * 8];
#pragma unroll
      for (int ns = 0; ns < NS; ++ns)
        bf[ns] = *(const short8*)&Bs[(brow + ns * 16) * 64 + slot * 8];
#pragma unroll
      for (int ms = 0; ms < 4; ++ms)
#pragma unroll
        for (int ns = 0; ns < NS; ++ns)
          acc[ms][ns] = __builtin_amdgcn_mfma_f32_16x16x32_bf16(af[ms], bf[ns], acc[ms][ns], 0, 0, 0);
    }
  }

  u16* part = SPLIT ? ((u16*)Cout + (size_t)blockIdx.z * M * N) : nullptr;
#pragma unroll
  for (int ms = 0; ms < 4; ++ms)
#pragma unroll
    for (int ns = 0; ns < NS; ++ns)
#pragma unroll
      for (int r = 0; r < 4; ++r) {
        int grow = m0 + wr * 64 + ms * 16 + quad * 4 + r;
        int gcol = n0 + wc * (TN / 2) + ns * 16 + ln16;
        size_t idx = (size_t)grow * N + gcol;
        if (SPLIT) {
          part[idx] = f2bf(acc[ms][ns][r]);
        } else {
          float v = acc[ms][ns][r] + bias[gcol];
          if (GELU) v = 0.5f * v * (1.f + erff(v * 0.70710678118654752f));
          if (RESIDF) v += resid[idx];
          if (OUTF32) ((float*)Cout)[idx] = v;
          else        ((u16*)Cout)[idx] = f2bf(v);
        }
      }
}

// ---------------------------------------------------------------------------
// Flash-style causal attention, paired q-tiles, fixed-max softmax, SPLIT-2 by
// kt parity. Block (pair, h, b*2+s): handles q-tiles {pair, 31-pair}, k-tiles
// kt = s, s+2, ... -> ~16.5 balanced iters/block; grid 1024 = 4 blocks/CU.
// Partials: oPart bf16 [s][b][h][qt32][64][64] (UNnormalized), lPart f32
// [s][b][h][qt][64]. merge_attn_k combines (no max rescale needed).
// ---------------------------------------------------------------------------
__global__ __launch_bounds__(256) void attn_k(const u16* __restrict__ qkv,
                                              const u16* __restrict__ vT,
                                              u16* __restrict__ oPart,
                                              float* __restrict__ lPart) {
  __shared__ u16 Ks[64 * 64];
  __shared__ u16 Vs[64 * 64];
  __shared__ u16 Ps[2][4][16][72];
  int pair = blockIdx.x, h = blockIdx.y;
  int b = blockIdx.z >> 1, s = blockIdx.z & 1;
  int qtT[2] = {pair, 31 - pair};
  int t = threadIdx.x, wave = t >> 6, lane = t & 63;
  int ln16 = lane & 15, quad = lane >> 4;

  int qbase[2] = {qtT[0] * 64 + wave * 16, qtT[1] * 64 + wave * 16};
  short8 aq[2][2];
#pragma unroll
  for (int i = 0; i < 2; ++i) {
    const u16* qrow = qkv + (size_t)(b * 2048 + qbase[i] + ln16) * 3072 + h * 64;
    aq[i][0] = *(const short8*)(qrow + quad * 8);
    aq[i][1] = *(const short8*)(qrow + 32 + quad * 8);
  }

  f32x4 zero4 = {0.f, 0.f, 0.f, 0.f};
  f32x4 o[2][4];
  float l_i[2][4];
#pragma unroll
  for (int i = 0; i < 2; ++i)
#pragma unroll
    for (int n = 0; n < 4; ++n) { o[i][n] = zero4; l_i[i][n] = 0.f; }

  int lrow = lane >> 3;
  int gseg = (lane & 7) ^ lrow;
  const u16* kB = qkv + (size_t)(b * 2048 + wave * 16 + lrow) * 3072 + 1024 + h * 64 + gseg * 8;
  const u16* vB = vT + ((size_t)(b * 16 + h) * 64 + wave * 16 + lrow) * 2048 + gseg * 8;
  u16* kL = Ks + wave * 16 * 64;
  u16* vL = Vs + wave * 16 * 64;

  const float SC = 0.125f * 1.44269504088896340736f;
  int e = ln16 & 7;
  int nkt = qtT[1] + 1;
  for (int kt = s; kt < nkt; kt += 2) {
    __syncthreads();
    size_t kOff = (size_t)kt * 64 * 3072;
    size_t vOff = (size_t)kt * 64;
#pragma unroll
    for (int i = 0; i < 2; ++i) {
      load_lds16(kB + kOff + (size_t)i * 8 * 3072, kL + i * 8 * 64);
      load_lds16(vB + vOff + (size_t)i * 8 * 2048, vL + i * 8 * 64);
    }
    __syncthreads();

    int kg = kt * 64;
#pragma unroll
    for (int i = 0; i < 2; ++i) {
      if (i == 0 && kt > qtT[0]) continue;
      f32x4 sreg[4] = {zero4, zero4, zero4, zero4};
#pragma unroll
      for (int kk = 0; kk < 2; ++kk) {
        short8 a = aq[i][kk];
        int slot = (kk * 4 + quad) ^ e;
#pragma unroll
        for (int n = 0; n < 4; ++n) {
          short8 kb = *(const short8*)&Ks[(n * 16 + ln16) * 64 + slot * 8];
          sreg[n] = __builtin_amdgcn_mfma_f32_16x16x32_bf16(a, kb, sreg[n], 0, 0, 0);
        }
      }
#pragma unroll
      for (int r = 0; r < 4; ++r) {
        int gq = qbase[i] + quad * 4 + r;
        float sum = 0.f;
#pragma unroll
        for (int n = 0; n < 4; ++n) {
          float p = (kg + n * 16 + ln16 > gq) ? 0.f : exp2f(sreg[n][r] * SC);
          sum += p;
          Ps[i][wave][quad * 4 + r][n * 16 + ln16] = f2bf(p);
        }
#pragma unroll
        for (int off = 8; off; off >>= 1) sum += __shfl_xor(sum, off, 16);
        l_i[i][r] += sum;
      }
#pragma unroll
      for (int kk = 0; kk < 2; ++kk) {
        short8 ap = *(const short8*)&Ps[i][wave][ln16][kk * 32 + quad * 8];
        int slot = (kk * 4 + quad) ^ e;
#pragma unroll
        for (int n = 0; n < 4; ++n) {
          short8 bv = *(const short8*)&Vs[(n * 16 + ln16) * 64 + slot * 8];
          o[i][n] = __builtin_amdgcn_mfma_f32_16x16x32_bf16(ap, bv, o[i][n], 0, 0, 0);
        }
      }
    }
  }

#pragma unroll
  for (int i = 0; i < 2; ++i) {
    size_t base = ((((size_t)(s * 2 + b) * 16 + h) * 32 + qtT[i]) * 64);
#pragma unroll
    for (int n = 0; n < 4; ++n)
#pragma unroll
      for (int r = 0; r < 4; ++r) {
        int row = wave * 16 + quad * 4 + r;
        oPart[(base + row) * 64 + n * 16 + ln16] = f2bf(o[i][n][r]);
      }
    if (ln16 == 0)
#pragma unroll
      for (int r = 0; r < 4; ++r)
        lPart[base + wave * 16 + quad * 4 + r] = l_i[i][r];
  }
}

// ---------------------------------------------------------------------------
// Attention split merge: z = (o0+o1)/(l0+l1). 4096 blocks x 256 thr, 4 cols
// per thread (one ushort4 per partial).
// ---------------------------------------------------------------------------
__global__ __launch_bounds__(256) void merge_attn_k(const u16* __restrict__ oPart,
                                                    const float* __restrict__ lPart,
                                                    u16* __restrict__ z) {
  const size_t S = (size_t)2 * 16 * 32 * 64 * 64;   // o stride between s-halves
  const size_t L = (size_t)2 * 16 * 32 * 64;        // l stride
  unsigned tid = blockIdx.x * 256 + threadIdx.x;
  int c4  = tid & 15;
  int row = (tid >> 4) & 63;
  int qt  = (tid >> 10) & 31;
  int h   = (tid >> 15) & 15;
  int b   = tid >> 19;
  size_t lIdx = (((size_t)(b * 16 + h) * 32 + qt) * 64 + row);
  size_t pIdx = lIdx * 64 + c4 * 4;
  float inv = 1.f / (lPart[lIdx] + lPart[L + lIdx]);
  ushort4 a0 = *(const ushort4*)(oPart + pIdx);
  ushort4 a1 = *(const ushort4*)(oPart + S + pIdx);
  ushort4 r;
  r.x = f2bf((bf2f(a0.x) + bf2f(a1.x)) * inv);
  r.y = f2bf((bf2f(a0.y) + bf2f(a1.y)) * inv);
  r.z = f2bf((bf2f(a0.z) + bf2f(a1.z)) * inv);
  r.w = f2bf((bf2f(a0.w) + bf2f(a1.w)) * inv);
  *(ushort4*)(z + (size_t)(b * 2048 + qt * 64 + row) * 1024 + h * 64 + c4 * 4) = r;
}

// ---------------------------------------------------------------------------
extern "C" void kernel_launch(void* const* d_in, const int* in_sizes, int n_in,
                              void* d_out, int out_size, void* d_ws, size_t ws_size,
                              hipStream_t stream) {
  const float* resid_pre = (const float*)d_in[0];
  const float* ln1_w = (const float*)d_in[1];
  const float* ln1_b = (const float*)d_in[2];
  const float* W_Q  = (const float*)d_in[3];
  const float* b_Q  = (const float*)d_in[4];
  const float* W_K  = (const float*)d_in[5];
  const float* b_K  = (const float*)d_in[6];
  const float* W_V  = (const float*)d_in[7];
  const float* b_V  = (const float*)d_in[8];
  const float* W_O  = (const float*)d_in[9];
  const float* b_O  = (const float*)d_in[10];
  const float* ln2_w = (const float*)d_in[11];
  const float* ln2_b = (const float*)d_in[12];
  const float* W_in  = (const float*)d_in[13];
  const float* b_in  = (const float*)d_in[14];
  const float* W_out = (const float*)d_in[15];
  const float* b_out = (const float*)d_in[16];
  float* out = (float*)d_out;

  char* w = (char*)d_ws;
  u16* WqkvT = (u16*)w;  w += (size_t)3072 * 1024 * 2;
  u16* WoT   = (u16*)w;  w += (size_t)1024 * 1024 * 2;
  u16* WinT  = (u16*)w;  w += (size_t)4096 * 1024 * 2;
  u16* WoutT = (u16*)w;  w += (size_t)1024 * 4096 * 2;
  float* qkvBias = (float*)w; w += 3072 * 4;
  char* xr   = w;                                        // xln + resid_mid region
  u16* xln   = (u16*)w;  w += (size_t)4096 * 1024 * 2;   // reused as y after LN2
  float* resid_mid = (float*)w; w += (size_t)4096 * 1024 * 4;
  u16* qkvBuf = (u16*)w; w += (size_t)4096 * 3072 * 2;
  u16* zBuf  = (u16*)w;  w += (size_t)4096 * 1024 * 2;
  u16* vTBuf = (u16*)w;  w += (size_t)32 * 64 * 2048 * 2;
  u16* partP = (u16*)w;  w += (size_t)2 * 4096 * 1024 * 2;  // proj/down split partials
  u16* hBuf  = qkvBuf;   // 32 MB: reuses qkvBuf+zBuf region (dead by then)
  // attn partials overlap xln+resid_mid (both dead during attention)
  u16*   oPart = (u16*)xr;                                        // 16.78 MB
  float* lPart = (float*)(xr + (size_t)2 * 2 * 16 * 32 * 64 * 64 * 2);  // +0.52 MB

  dim3 tb(32, 8);
  prep_k<<<12289, tb, 0, stream>>>(W_Q, W_K, W_V, W_O, W_in, W_out,
                                   b_Q, b_K, b_V,
                                   WqkvT, WoT, WinT, WoutT, qkvBias);

  // LN1: fp32 resid_pre -> bf16 xln
  ln_k<<<4096, 256, 0, stream>>>(resid_pre, ln1_w, ln1_b, xln);
  // QKV projection (fused): [4096,1024] x [1024,3072] -> bf16
  gemm_k<128, false, false, false, false><<<dim3(24, 32), 256, 0, stream>>>(
      xln, WqkvT, qkvBias, nullptr, qkvBuf, 4096, 3072, 1024, 1024, 1024);
  // V transpose for attention B-fragments
  transpose_v_k<<<dim3(2, 64, 32), tb, 0, stream>>>(qkvBuf, vTBuf);
  // Causal attention, split-2 by kt parity (xln/resid_mid dead -> oPart there)
  attn_k<<<dim3(16, 16, 4), 256, 0, stream>>>(qkvBuf, vTBuf, oPart, lPart);
  merge_attn_k<<<4096, 256, 0, stream>>>(oPart, lPart, zBuf);
  // Output projection, split-K x2 -> bf16 partials
  gemm_k<64, false, false, false, true><<<dim3(16, 32, 2), 256, 0, stream>>>(
      zBuf, WoT, nullptr, nullptr, partP, 4096, 1024, 512, 1024, 1024);
  // Fused merge + residual + LN2 -> resid_mid (fp32) + xln (bf16)
  merge_ln_k<<<4096, 256, 0, stream>>>(partP, b_O, resid_pre, resid_mid,
                                       ln2_w, ln2_b, xln);
  // MLP up + exact GELU -> bf16 h
  gemm_k<128, false, true, false, false><<<dim3(32, 32), 256, 0, stream>>>(
      xln, WinT, b_in, nullptr, hBuf, 4096, 4096, 1024, 1024, 1024);
  // MLP down, split-K x2 -> bf16 partials
  gemm_k<64, false, false, false, true><<<dim3(16, 32, 2), 256, 0, stream>>>(
      hBuf, WoutT, nullptr, nullptr, partP, 4096, 1024, 2048, 4096, 4096);
  // Final merge + bias + residual -> out (fp32)
  merge_out_k<<<4096, 256, 0, stream>>>(partP, b_out, resid_mid, out);
}

// Round 9
// 365.456 us; speedup vs baseline: 1.0155x; 1.0155x over previous
//
#include <hip/hip_runtime.h>
#include <cstddef>

typedef unsigned short u16;
using short8 = __attribute__((ext_vector_type(8))) short;
using f32x4  = __attribute__((ext_vector_type(4))) float;

__device__ __forceinline__ float bf2f(u16 u) {
  union { unsigned int i; float f; } v; v.i = ((unsigned int)u) << 16; return v.f;
}
__device__ __forceinline__ u16 f2bf(float f) {
  __bf16 h = (__bf16)f;
  return __builtin_bit_cast(unsigned short, h);
}

// async global(16B/lane) -> LDS. lds dest must be wave-uniform base; HW adds lane*16.
__device__ __forceinline__ void load_lds16(const u16* g, u16* l) {
  __builtin_amdgcn_global_load_lds((const __attribute__((address_space(1))) void*)g,
                                   (__attribute__((address_space(3))) void*)l, 16, 0, 0);
}

// ---------------------------------------------------------------------------
// prep_k: ALL weight transposes (fp32 [R][C] -> bf16 [C][R]) + qkv bias concat.
// Block (32,8). Ranges: [0,3072) WQ/WK/WV; [3072,4096) W_O; [4096,8192) W_in;
// [8192,12288) W_out; 12288 bias concat.
// ---------------------------------------------------------------------------
__global__ __launch_bounds__(256) void prep_k(const float* __restrict__ wq,
                                              const float* __restrict__ wk,
                                              const float* __restrict__ wv,
                                              const float* __restrict__ wo,
                                              const float* __restrict__ win,
                                              const float* __restrict__ wout,
                                              const float* __restrict__ bq,
                                              const float* __restrict__ bk,
                                              const float* __restrict__ bv,
                                              u16* __restrict__ wqkvT,
                                              u16* __restrict__ woT,
                                              u16* __restrict__ winT,
                                              u16* __restrict__ woutT,
                                              float* __restrict__ qkvBias) {
  __shared__ float tile[32][33];
  int id = blockIdx.x;
  int tx = threadIdx.x, ty = threadIdx.y;

  if (id == 12288) {               // bias concat
    int t = ty * 32 + tx;
#pragma unroll
    for (int i = 0; i < 12; ++i) {
      int idx = i * 256 + t;
      float v = (idx < 1024) ? bq[idx] : (idx < 2048) ? bk[idx - 1024] : bv[idx - 2048];
      qkvBias[idx] = v;
    }
    return;
  }

  const float* in; u16* out; int R, C, c0, r0;
  if (id < 3072) {                 // W_Q / W_K / W_V, per-head
    int s = id >> 10, r = id & 1023;
    int h = r >> 6, tt = r & 63;
    const float* W = (s == 0) ? wq : (s == 1) ? wk : wv;
    in = W + h * 65536;
    out = wqkvT + (size_t)s * 1024 * 1024 + h * 64 * 1024;
    R = 1024; C = 64;
    c0 = (tt & 1) * 32; r0 = (tt >> 1) * 32;
  } else if (id < 4096) {          // W_O
    int tt = id - 3072;
    in = wo; out = woT; R = 1024; C = 1024;
    c0 = (tt & 31) * 32; r0 = (tt >> 5) * 32;
  } else if (id < 8192) {          // W_in
    int tt = id - 4096;
    in = win; out = winT; R = 1024; C = 4096;
    c0 = (tt & 127) * 32; r0 = (tt >> 7) * 32;
  } else {                         // W_out
    int tt = id - 8192;
    in = wout; out = woutT; R = 4096; C = 1024;
    c0 = (tt & 31) * 32; r0 = (tt >> 5) * 32;
  }

#pragma unroll
  for (int i = 0; i < 32; i += 8)
    tile[ty + i][tx] = in[(size_t)(r0 + ty + i) * C + c0 + tx];
  __syncthreads();
#pragma unroll
  for (int i = 0; i < 32; i += 8)
    out[(size_t)(c0 + ty + i) * R + r0 + tx] = f2bf(tile[tx][ty + i]);
}

// ---------------------------------------------------------------------------
// V transpose: qkv [b*2048][3072] (V at col 2048+h*64+e) -> vT[(b*16+h)*64+e][2048]
// Grid (2, 64, 32), block (32,8).
// ---------------------------------------------------------------------------
__global__ __launch_bounds__(256) void transpose_v_k(const u16* __restrict__ qkv,
                                                     u16* __restrict__ vT) {
  __shared__ u16 tile[32][33];
  int bh = blockIdx.z;
  int b = bh >> 4, h = bh & 15;
  const u16* in = qkv + (size_t)b * 2048 * 3072 + 2048 + h * 64;
  u16* out = vT + (size_t)bh * 64 * 2048;
  int e0 = blockIdx.x * 32, s0 = blockIdx.y * 32;
  int tx = threadIdx.x, ty = threadIdx.y;
#pragma unroll
  for (int i = 0; i < 32; i += 8)
    tile[ty + i][tx] = in[(size_t)(s0 + ty + i) * 3072 + e0 + tx];
  __syncthreads();
#pragma unroll
  for (int i = 0; i < 32; i += 8)
    out[(size_t)(e0 + ty + i) * 2048 + s0 + tx] = tile[tx][ty + i];
}

// ---------------------------------------------------------------------------
// LayerNorm over D=1024, fp32 in -> bf16 out. One block (256 thr) per row.
// ---------------------------------------------------------------------------
__global__ __launch_bounds__(256) void ln_k(const float* __restrict__ inp,
                                            const float* __restrict__ w,
                                            const float* __restrict__ bias,
                                            u16* __restrict__ out) {
  __shared__ float red[2][4];
  int row = blockIdx.x, t = threadIdx.x;
  int wave = t >> 6, lane = t & 63;
  size_t base = (size_t)row * 1024 + t * 4;
  float4 f = *(const float4*)(inp + base);
  float v[4] = {f.x, f.y, f.z, f.w};
  float s = v[0] + v[1] + v[2] + v[3];
#pragma unroll
  for (int off = 32; off; off >>= 1) s += __shfl_xor(s, off, 64);
  if (lane == 0) red[0][wave] = s;
  __syncthreads();
  float mean = (red[0][0] + red[0][1] + red[0][2] + red[0][3]) * (1.f / 1024.f);
  float c[4]; float sq = 0.f;
#pragma unroll
  for (int j = 0; j < 4; ++j) { c[j] = v[j] - mean; sq += c[j] * c[j]; }
#pragma unroll
  for (int off = 32; off; off >>= 1) sq += __shfl_xor(sq, off, 64);
  if (lane == 0) red[1][wave] = sq;
  __syncthreads();
  float var = (red[1][0] + red[1][1] + red[1][2] + red[1][3]) * (1.f / 1024.f);
  float inv = 1.f / sqrtf(var + 1e-5f);
  float4 wv = *(const float4*)(w + t * 4);
  float4 bv = *(const float4*)(bias + t * 4);
  out[base + 0] = f2bf(c[0] * inv * wv.x + bv.x);
  out[base + 1] = f2bf(c[1] * inv * wv.y + bv.y);
  out[base + 2] = f2bf(c[2] * inv * wv.z + bv.z);
  out[base + 3] = f2bf(c[3] * inv * wv.w + bv.w);
}

// ---------------------------------------------------------------------------
// Fused proj-split-merge + residual + LN2: one block per row.
// ---------------------------------------------------------------------------
__global__ __launch_bounds__(256) void merge_ln_k(const u16* __restrict__ p,  // [2][4096][1024] bf16
                                                  const float* __restrict__ bO,
                                                  const float* __restrict__ resid_pre,
                                                  float* __restrict__ resid_mid,
                                                  const float* __restrict__ w,
                                                  const float* __restrict__ bias,
                                                  u16* __restrict__ out) {
  __shared__ float red[2][4];
  const size_t S = (size_t)4096 * 1024;
  int row = blockIdx.x, t = threadIdx.x;
  int wave = t >> 6, lane = t & 63;
  size_t base = (size_t)row * 1024 + t * 4;
  float4 f = *(const float4*)(resid_pre + base);
  float4 bo = *(const float4*)(bO + t * 4);
  ushort4 a0 = *(const ushort4*)(p + base);
  ushort4 a1 = *(const ushort4*)(p + S + base);
  float v[4];
  v[0] = f.x + bo.x + bf2f(a0.x) + bf2f(a1.x);
  v[1] = f.y + bo.y + bf2f(a0.y) + bf2f(a1.y);
  v[2] = f.z + bo.z + bf2f(a0.z) + bf2f(a1.z);
  v[3] = f.w + bo.w + bf2f(a0.w) + bf2f(a1.w);
  *(float4*)(resid_mid + base) = (float4){v[0], v[1], v[2], v[3]};
  float s = v[0] + v[1] + v[2] + v[3];
#pragma unroll
  for (int off = 32; off; off >>= 1) s += __shfl_xor(s, off, 64);
  if (lane == 0) red[0][wave] = s;
  __syncthreads();
  float mean = (red[0][0] + red[0][1] + red[0][2] + red[0][3]) * (1.f / 1024.f);
  float c[4]; float sq = 0.f;
#pragma unroll
  for (int j = 0; j < 4; ++j) { c[j] = v[j] - mean; sq += c[j] * c[j]; }
#pragma unroll
  for (int off = 32; off; off >>= 1) sq += __shfl_xor(sq, off, 64);
  if (lane == 0) red[1][wave] = sq;
  __syncthreads();
  float var = (red[1][0] + red[1][1] + red[1][2] + red[1][3]) * (1.f / 1024.f);
  float inv = 1.f / sqrtf(var + 1e-5f);
  float4 wv = *(const float4*)(w + t * 4);
  float4 bv = *(const float4*)(bias + t * 4);
  out[base + 0] = f2bf(c[0] * inv * wv.x + bv.x);
  out[base + 1] = f2bf(c[1] * inv * wv.y + bv.y);
  out[base + 2] = f2bf(c[2] * inv * wv.z + bv.z);
  out[base + 3] = f2bf(c[3] * inv * wv.w + bv.w);
}

// ---------------------------------------------------------------------------
// MLP-down split merge: out = resid_mid + b_out + p0 + p1. One block per row.
// ---------------------------------------------------------------------------
__global__ __launch_bounds__(256) void merge_out_k(const u16* __restrict__ p,  // [2][4096][1024] bf16
                                                   const float* __restrict__ bout,
                                                   const float* __restrict__ resid_mid,
                                                   float* __restrict__ out) {
  const size_t S = (size_t)4096 * 1024;
  int row = blockIdx.x, t = threadIdx.x;
  size_t base = (size_t)row * 1024 + t * 4;
  float4 f = *(const float4*)(resid_mid + base);
  float4 bo = *(const float4*)(bout + t * 4);
  ushort4 a0 = *(const ushort4*)(p + base);
  ushort4 a1 = *(const ushort4*)(p + S + base);
  float4 r;
  r.x = f.x + bo.x + bf2f(a0.x) + bf2f(a1.x);
  r.y = f.y + bo.y + bf2f(a0.y) + bf2f(a1.y);
  r.z = f.z + bo.z + bf2f(a0.z) + bf2f(a1.z);
  r.w = f.w + bo.w + bf2f(a0.w) + bf2f(a1.w);
  *(float4*)(out + base) = r;
}

// ---------------------------------------------------------------------------
// m97-class MFMA GEMM: C[M][N] = A[M][*](bf16) * BT[N][*](bf16)^T (+bias...).
// 128xTN tile, BK=64, global_load_lds staging, XOR-swizzled LDS.
// SPLIT: blockIdx.z selects K-slab; writes bf16 partial at Cout + z*M*N.
// ---------------------------------------------------------------------------
template<int TN, bool RESIDF, bool GELU, bool OUTF32, bool SPLIT>
__global__ __launch_bounds__(256, 2) void gemm_k(const u16* __restrict__ A,
                                                 const u16* __restrict__ BT,
                                                 const float* __restrict__ bias,
                                                 const float* __restrict__ resid,
                                                 void* __restrict__ Cout,
                                                 int M, int N, int K,
                                                 int lda, int ldb) {
  constexpr int NS = TN / 32;
  __shared__ u16 As[128 * 64];
  __shared__ u16 Bs[TN * 64];
  int n0 = blockIdx.x * TN, m0 = blockIdx.y * 128;
  int koff = SPLIT ? blockIdx.z * K : 0;
  int t = threadIdx.x;
  int wave = t >> 6, lane = t & 63;
  int wr = wave >> 1, wc = wave & 1;
  int ln16 = lane & 15, quad = lane >> 4;

  f32x4 acc[4][NS];
#pragma unroll
  for (int i = 0; i < 4; ++i)
#pragma unroll
    for (int j = 0; j < NS; ++j) acc[i][j] = (f32x4){0.f, 0.f, 0.f, 0.f};

  int lrow8 = lane >> 3;
  int gseg  = (lane & 7) ^ lrow8;
  const u16* aG = A  + (size_t)(m0 + wave * 8 + lrow8) * lda + koff + gseg * 8;
  const u16* bG = BT + (size_t)(n0 + wave * 8 + lrow8) * ldb + koff + gseg * 8;
  u16* aL = As + wave * 8 * 64;
  u16* bL = Bs + wave * 8 * 64;

  int e = ln16 & 7;
  int arow = wr * 64 + ln16;
  int brow = wc * (TN / 2) + ln16;

  for (int k0 = 0; k0 < K; k0 += 64) {
    __syncthreads();
#pragma unroll
    for (int i = 0; i < 4; ++i)
      load_lds16(aG + (size_t)i * 32 * lda + k0, aL + i * 32 * 64);
#pragma unroll
    for (int i = 0; i < TN / 32; ++i)
      load_lds16(bG + (size_t)i * 32 * ldb + k0, bL + i * 32 * 64);
    __syncthreads();
#pragma unroll
    for (int kk = 0; kk < 2; ++kk) {
      int slot = (kk * 4 + quad) ^ e;
      short8 af[4], bf[NS];
#pragma unroll
      for (int ms = 0; ms < 4; ++ms)
        af[ms] = *(const short8*)&As[(arow + ms * 16) * 64 + slot * 8];
#pragma unroll
      for (int ns = 0; ns < NS; ++ns)
        bf[ns] = *(const short8*)&Bs[(brow + ns * 16) * 64 + slot * 8];
#pragma unroll
      for (int ms = 0; ms < 4; ++ms)
#pragma unroll
        for (int ns = 0; ns < NS; ++ns)
          acc[ms][ns] = __builtin_amdgcn_mfma_f32_16x16x32_bf16(af[ms], bf[ns], acc[ms][ns], 0, 0, 0);
    }
  }

  u16* part = SPLIT ? ((u16*)Cout + (size_t)blockIdx.z * M * N) : nullptr;
#pragma unroll
  for (int ms = 0; ms < 4; ++ms)
#pragma unroll
    for (int ns = 0; ns < NS; ++ns)
#pragma unroll
      for (int r = 0; r < 4; ++r) {
        int grow = m0 + wr * 64 + ms * 16 + quad * 4 + r;
        int gcol = n0 + wc * (TN / 2) + ns * 16 + ln16;
        size_t idx = (size_t)grow * N + gcol;
        if (SPLIT) {
          part[idx] = f2bf(acc[ms][ns][r]);
        } else {
          float v = acc[ms][ns][r] + bias[gcol];
          if (GELU) v = 0.5f * v * (1.f + erff(v * 0.70710678118654752f));
          if (RESIDF) v += resid[idx];
          if (OUTF32) ((float*)Cout)[idx] = v;
          else        ((u16*)Cout)[idx] = f2bf(v);
        }
      }
}

// ---------------------------------------------------------------------------
// Flash-style causal attention, paired q-tiles, fixed-max softmax, SPLIT-2 by
// kt parity. v3: K/V MFMA fragments loaded ONCE per kk and shared by both
// q-subtiles (tile A + tile B per wave); l-reduction deferred out of the
// k-loop (fixed-max softmax is linear -> per-lane partials, one reduce at
// end). Cuts LDS-pipe ops ~40% while keeping the 33-iteration per-block
// balance. Partials: oPart bf16 [s][b][h][qt][64][64] unnormalized, lPart
// f32 [s][b][h][qt][64].
// ---------------------------------------------------------------------------
__global__ __launch_bounds__(256, 4) void attn_k(const u16* __restrict__ qkv,
                                                 const u16* __restrict__ vT,
                                                 u16* __restrict__ oPart,
                                                 float* __restrict__ lPart) {
  __shared__ u16 Ks[64 * 64];
  __shared__ u16 Vs[64 * 64];
  __shared__ u16 Ps[4][32][72];
  int pair = blockIdx.x, h = blockIdx.y;
  int b = blockIdx.z >> 1, s = blockIdx.z & 1;
  int qtT[2] = {pair, 31 - pair};
  int t = threadIdx.x, wave = t >> 6, lane = t & 63;
  int ln16 = lane & 15, quad = lane >> 4;

  int qbase[2] = {qtT[0] * 64 + wave * 16, qtT[1] * 64 + wave * 16};
  short8 aq[2][2];
#pragma unroll
  for (int i = 0; i < 2; ++i) {
    const u16* qrow = qkv + (size_t)(b * 2048 + qbase[i] + ln16) * 3072 + h * 64;
    aq[i][0] = *(const short8*)(qrow + quad * 8);
    aq[i][1] = *(const short8*)(qrow + 32 + quad * 8);
  }

  f32x4 zero4 = {0.f, 0.f, 0.f, 0.f};
  f32x4 o[2][4];
  float lsum[2][4];
#pragma unroll
  for (int i = 0; i < 2; ++i)
#pragma unroll
    for (int n = 0; n < 4; ++n) { o[i][n] = zero4; lsum[i][n] = 0.f; }

  int lrow = lane >> 3;
  int gseg = (lane & 7) ^ lrow;
  const u16* kB = qkv + (size_t)(b * 2048 + wave * 16 + lrow) * 3072 + 1024 + h * 64 + gseg * 8;
  const u16* vB = vT + ((size_t)(b * 16 + h) * 64 + wave * 16 + lrow) * 2048 + gseg * 8;
  u16* kL = Ks + wave * 16 * 64;
  u16* vL = Vs + wave * 16 * 64;

  const float SC = 0.125f * 1.44269504088896340736f;
  int e = ln16 & 7;
  int nkt = qtT[1] + 1;
  for (int kt = s; kt < nkt; kt += 2) {
    __syncthreads();
    size_t kOff = (size_t)kt * 64 * 3072;
    size_t vOff = (size_t)kt * 64;
#pragma unroll
    for (int i = 0; i < 2; ++i) {
      load_lds16(kB + kOff + (size_t)i * 8 * 3072, kL + i * 8 * 64);
      load_lds16(vB + vOff + (size_t)i * 8 * 2048, vL + i * 8 * 64);
    }
    __syncthreads();

    bool bothA = (kt <= qtT[0]);
    int kg = kt * 64;
    f32x4 sr[2][4];
#pragma unroll
    for (int i = 0; i < 2; ++i)
#pragma unroll
      for (int n = 0; n < 4; ++n) sr[i][n] = zero4;

    // QK: load each K fragment once, use for both q-subtiles
#pragma unroll
    for (int kk = 0; kk < 2; ++kk) {
      int slot = (kk * 4 + quad) ^ e;
      short8 kb[4];
#pragma unroll
      for (int n = 0; n < 4; ++n)
        kb[n] = *(const short8*)&Ks[(n * 16 + ln16) * 64 + slot * 8];
#pragma unroll
      for (int n = 0; n < 4; ++n)
        sr[1][n] = __builtin_amdgcn_mfma_f32_16x16x32_bf16(aq[1][kk], kb[n], sr[1][n], 0, 0, 0);
      if (bothA) {
#pragma unroll
        for (int n = 0; n < 4; ++n)
          sr[0][n] = __builtin_amdgcn_mfma_f32_16x16x32_bf16(aq[0][kk], kb[n], sr[0][n], 0, 0, 0);
      }
    }

    // softmax (fixed max, per-lane l partials only — no in-loop reduction)
#pragma unroll
    for (int i = 0; i < 2; ++i) {
      if (i == 0 && !bothA) continue;
#pragma unroll
      for (int r = 0; r < 4; ++r) {
        int gq = qbase[i] + quad * 4 + r;
#pragma unroll
        for (int n = 0; n < 4; ++n) {
          float p = (kg + n * 16 + ln16 > gq) ? 0.f : exp2f(sr[i][n][r] * SC);
          lsum[i][r] += p;
          Ps[wave][i * 16 + quad * 4 + r][n * 16 + ln16] = f2bf(p);
        }
      }
    }

    // PV: load each V fragment once, use for both q-subtiles
#pragma unroll
    for (int kk = 0; kk < 2; ++kk) {
      int slot = (kk * 4 + quad) ^ e;
      short8 vb[4];
#pragma unroll
      for (int n = 0; n < 4; ++n)
        vb[n] = *(const short8*)&Vs[(n * 16 + ln16) * 64 + slot * 8];
#pragma unroll
      for (int i = 0; i < 2; ++i) {
        if (i == 0 && !bothA) continue;
        short8 ap = *(const short8*)&Ps[wave][i * 16 + ln16][kk * 32 + quad * 8];
#pragma unroll
        for (int n = 0; n < 4; ++n)
          o[i][n] = __builtin_amdgcn_mfma_f32_16x16x32_bf16(ap, vb[n], o[i][n], 0, 0, 0);
      }
    }
  }

  // deferred 16-lane l reduction (once per wave)
#pragma unroll
  for (int i = 0; i < 2; ++i) {
    float lred[4];
#pragma unroll
    for (int r = 0; r < 4; ++r) {
      float v = lsum[i][r];
#pragma unroll
      for (int off = 8; off; off >>= 1) v += __shfl_xor(v, off, 16);
      lred[r] = v;
    }
    size_t base = ((((size_t)(s * 2 + b) * 16 + h) * 32 + qtT[i]) * 64);
#pragma unroll
    for (int n = 0; n < 4; ++n)
#pragma unroll
      for (int r = 0; r < 4; ++r) {
        int row = wave * 16 + quad * 4 + r;
        oPart[(base + row) * 64 + n * 16 + ln16] = f2bf(o[i][n][r]);
      }
    if (ln16 == 0)
#pragma unroll
      for (int r = 0; r < 4; ++r)
        lPart[base + wave * 16 + quad * 4 + r] = lred[r];
  }
}

// ---------------------------------------------------------------------------
// Attention split merge: z = (o0+o1)/(l0+l1). 4096 blocks x 256 thr.
// ---------------------------------------------------------------------------
__global__ __launch_bounds__(256) void merge_attn_k(const u16* __restrict__ oPart,
                                                    const float* __restrict__ lPart,
                                                    u16* __restrict__ z) {
  const size_t S = (size_t)2 * 16 * 32 * 64 * 64;   // o stride between s-halves
  const size_t L = (size_t)2 * 16 * 32 * 64;        // l stride
  unsigned tid = blockIdx.x * 256 + threadIdx.x;
  int c4  = tid & 15;
  int row = (tid >> 4) & 63;
  int qt  = (tid >> 10) & 31;
  int h   = (tid >> 15) & 15;
  int b   = tid >> 19;
  size_t lIdx = (((size_t)(b * 16 + h) * 32 + qt) * 64 + row);
  size_t pIdx = lIdx * 64 + c4 * 4;
  float inv = 1.f / (lPart[lIdx] + lPart[L + lIdx]);
  ushort4 a0 = *(const ushort4*)(oPart + pIdx);
  ushort4 a1 = *(const ushort4*)(oPart + S + pIdx);
  ushort4 r;
  r.x = f2bf((bf2f(a0.x) + bf2f(a1.x)) * inv);
  r.y = f2bf((bf2f(a0.y) + bf2f(a1.y)) * inv);
  r.z = f2bf((bf2f(a0.z) + bf2f(a1.z)) * inv);
  r.w = f2bf((bf2f(a0.w) + bf2f(a1.w)) * inv);
  *(ushort4*)(z + (size_t)(b * 2048 + qt * 64 + row) * 1024 + h * 64 + c4 * 4) = r;
}

// ---------------------------------------------------------------------------
extern "C" void kernel_launch(void* const* d_in, const int* in_sizes, int n_in,
                              void* d_out, int out_size, void* d_ws, size_t ws_size,
                              hipStream_t stream) {
  const float* resid_pre = (const float*)d_in[0];
  const float* ln1_w = (const float*)d_in[1];
  const float* ln1_b = (const float*)d_in[2];
  const float* W_Q  = (const float*)d_in[3];
  const float* b_Q  = (const float*)d_in[4];
  const float* W_K  = (const float*)d_in[5];
  const float* b_K  = (const float*)d_in[6];
  const float* W_V  = (const float*)d_in[7];
  const float* b_V  = (const float*)d_in[8];
  const float* W_O  = (const float*)d_in[9];
  const float* b_O  = (const float*)d_in[10];
  const float* ln2_w = (const float*)d_in[11];
  const float* ln2_b = (const float*)d_in[12];
  const float* W_in  = (const float*)d_in[13];
  const float* b_in  = (const float*)d_in[14];
  const float* W_out = (const float*)d_in[15];
  const float* b_out = (const float*)d_in[16];
  float* out = (float*)d_out;

  char* w = (char*)d_ws;
  u16* WqkvT = (u16*)w;  w += (size_t)3072 * 1024 * 2;
  u16* WoT   = (u16*)w;  w += (size_t)1024 * 1024 * 2;
  u16* WinT  = (u16*)w;  w += (size_t)4096 * 1024 * 2;
  u16* WoutT = (u16*)w;  w += (size_t)1024 * 4096 * 2;
  float* qkvBias = (float*)w; w += 3072 * 4;
  char* xr   = w;                                        // xln + resid_mid region
  u16* xln   = (u16*)w;  w += (size_t)4096 * 1024 * 2;   // reused as y after LN2
  float* resid_mid = (float*)w; w += (size_t)4096 * 1024 * 4;
  u16* qkvBuf = (u16*)w; w += (size_t)4096 * 3072 * 2;
  u16* zBuf  = (u16*)w;  w += (size_t)4096 * 1024 * 2;
  u16* vTBuf = (u16*)w;  w += (size_t)32 * 64 * 2048 * 2;
  u16* partP = (u16*)w;  w += (size_t)2 * 4096 * 1024 * 2;  // proj/down split partials
  u16* hBuf  = qkvBuf;   // 32 MB: reuses qkvBuf+zBuf region (dead by then)
  // attn partials overlap xln+resid_mid (both dead during attention)
  u16*   oPart = (u16*)xr;                                        // 16.78 MB
  float* lPart = (float*)(xr + (size_t)2 * 2 * 16 * 32 * 64 * 64 * 2);  // +0.52 MB

  dim3 tb(32, 8);
  prep_k<<<12289, tb, 0, stream>>>(W_Q, W_K, W_V, W_O, W_in, W_out,
                                   b_Q, b_K, b_V,
                                   WqkvT, WoT, WinT, WoutT, qkvBias);

  // LN1: fp32 resid_pre -> bf16 xln
  ln_k<<<4096, 256, 0, stream>>>(resid_pre, ln1_w, ln1_b, xln);
  // QKV projection (fused): [4096,1024] x [1024,3072] -> bf16
  gemm_k<128, false, false, false, false><<<dim3(24, 32), 256, 0, stream>>>(
      xln, WqkvT, qkvBias, nullptr, qkvBuf, 4096, 3072, 1024, 1024, 1024);
  // V transpose for attention B-fragments
  transpose_v_k<<<dim3(2, 64, 32), tb, 0, stream>>>(qkvBuf, vTBuf);
  // Causal attention, split-2 by kt parity (xln/resid_mid dead -> oPart there)
  attn_k<<<dim3(16, 16, 4), 256, 0, stream>>>(qkvBuf, vTBuf, oPart, lPart);
  merge_attn_k<<<4096, 256, 0, stream>>>(oPart, lPart, zBuf);
  // Output projection, split-K x2 -> bf16 partials
  gemm_k<64, false, false, false, true><<<dim3(16, 32, 2), 256, 0, stream>>>(
      zBuf, WoT, nullptr, nullptr, partP, 4096, 1024, 512, 1024, 1024);
  // Fused merge + residual + LN2 -> resid_mid (fp32) + xln (bf16)
  merge_ln_k<<<4096, 256, 0, stream>>>(partP, b_O, resid_pre, resid_mid,
                                       ln2_w, ln2_b, xln);
  // MLP up + exact GELU -> bf16 h
  gemm_k<128, false, true, false, false><<<dim3(32, 32), 256, 0, stream>>>(
      xln, WinT, b_in, nullptr, hBuf, 4096, 4096, 1024, 1024, 1024);
  // MLP down, split-K x2 -> bf16 partials
  gemm_k<64, false, false, false, true><<<dim3(16, 32, 2), 256, 0, stream>>>(
      hBuf, WoutT, nullptr, nullptr, partP, 4096, 1024, 2048, 4096, 4096);
  // Final merge + bias + residual -> out (fp32)
  merge_out_k<<<4096, 256, 0, stream>>>(partP, b_out, resid_mid, out);
}